// Round 1
// 417.285 us; speedup vs baseline: 1.0466x; 1.0466x over previous
//
#include <hip/hip_runtime.h>
#include <hip/hip_fp16.h>

#define NN 100000
#define NE 3200000
#define H  64

#define BSHIFT 7
#define BNODES 128
#define NB ((NN + BNODES - 1) / BNODES)          // 782 buckets

#define PTHREADS 1024
#define PCHUNK   8192
#define PEPT     (PCHUNK / PTHREADS)             // 8
#define NPBLK    ((NE + PCHUNK - 1) / PCHUNK)    // 391

#define ECAP 6144                                // fixed per-bucket slot (mean 4092, sd ~64)

// ------- dispatch 1: encoder (verified) + block 0 zeroes bucket fill counters -------
__global__ __launch_bounds__(256) void encoder_kernel(
    const float* __restrict__ x,
    const float* __restrict__ W1, const float* __restrict__ b1,
    const float* __restrict__ W2, const float* __restrict__ b2,
    int* __restrict__ bfill,
    __half* __restrict__ h16)
{
    __shared__ float sh1[4][H];
    const int tid  = threadIdx.x;
    const int slot = tid >> 6;
    const int f    = tid & 63;
    const int node = blockIdx.x * 4 + slot;      // grid 25000 -> node < NN always

    if (blockIdx.x == 0) {                       // zero 782 fill counters (ws is poisoned)
        for (int i = tid; i < NB; i += 256) bfill[i] = 0;
    }

    {
        float acc = b1[f];
        #pragma unroll
        for (int k = 0; k < 6; ++k)
            acc = fmaf(x[node * 6 + k], W1[k * H + f], acc);
        sh1[slot][f] = fmaxf(acc, 0.0f);
    }
    __syncthreads();
    {
        float acc = b2[f];
        #pragma unroll 8
        for (int k = 0; k < H; ++k)
            acc = fmaf(sh1[slot][k], W2[k * H + f], acc);
        h16[node * H + f] = __float2half(acc);
    }
}

// ------- dispatch 2: partition -> fixed-slot bucket staging (verified R9 structure;
//         gbase now = b*ECAP + global fill reservation, no pre-scan needed) -------
__global__ __launch_bounds__(PTHREADS) void partition_kernel(
    const int* __restrict__ src, const int* __restrict__ dst,
    int* __restrict__ bfill, unsigned* __restrict__ staging)
{
    __shared__ unsigned stage[PCHUNK];   // 32 KB
    __shared__ int gpos[PCHUNK];         // 32 KB
    __shared__ int lh[NB];
    __shared__ int lcur[NB];
    __shared__ int gbase[NB];
    __shared__ int wtot[16];
    const int t = threadIdx.x;
    const int lane = t & 63;
    const int wid  = t >> 6;
    const int cbase = blockIdx.x * PCHUNK;
    const int cnt = min(PCHUNK, NE - cbase);

    for (int i = t; i < NB; i += PTHREADS) lh[i] = 0;
    __syncthreads();

    unsigned ent[PEPT];
    int bkt[PEPT];
    #pragma unroll
    for (int j = 0; j < PEPT; ++j) {
        const int idx = t + j * PTHREADS;
        if (idx < cnt) {
            const int s_ = src[cbase + idx];
            const int d_ = dst[cbase + idx];
            bkt[j] = s_ >> BSHIFT;
            ent[j] = (unsigned)d_ | ((unsigned)(s_ & (BNODES - 1)) << 17);
            atomicAdd(&lh[bkt[j]], 1);
        } else bkt[j] = -1;
    }
    __syncthreads();

    // wave-shfl exclusive scan over lh (verified R9)
    const int hv = (t < NB) ? lh[t] : 0;
    int incl = hv;
    #pragma unroll
    for (int off = 1; off < 64; off <<= 1) {
        const int n = __shfl_up(incl, off);
        if (lane >= off) incl += n;
    }
    if (lane == 63) wtot[wid] = incl;
    __syncthreads();
    if (wid == 0 && lane < 16) {
        const int v = wtot[lane];
        int s2 = v;
        #pragma unroll
        for (int off = 1; off < 16; off <<= 1) {
            const int n = __shfl_up(s2, off);
            if (lane >= off) s2 += n;
        }
        wtot[lane] = s2 - v;    // exclusive wave offsets
    }
    __syncthreads();
    if (t < NB) {
        const int excl = incl - hv + wtot[wid];
        lh[t]   = excl;
        lcur[t] = excl;
        gbase[t] = t * ECAP + ((hv > 0) ? atomicAdd(&bfill[t], hv) : 0);
    }
    __syncthreads();

    #pragma unroll
    for (int j = 0; j < PEPT; ++j) {
        if (bkt[j] >= 0) {
            const int lp = atomicAdd(&lcur[bkt[j]], 1);
            stage[lp] = ent[j];
            gpos[lp]  = gbase[bkt[j]] + (lp - lh[bkt[j]]);
        }
    }
    __syncthreads();

    for (int i = t; i < cnt; i += PTHREADS)
        staging[gpos[i]] = stage[i];
}

// ------- dispatch 3: bucket sort + per-node offs/counts (verified R13 structure) ----
__global__ __launch_bounds__(1024) void bucket_sort_kernel(
    const unsigned* __restrict__ staging, const int* __restrict__ bfill,
    int* __restrict__ sdst, int* __restrict__ offs, int* __restrict__ counts)
{
    __shared__ int ldst[ECAP];           // 24 KB
    __shared__ int cntS[BNODES];
    __shared__ int scanS[BNODES];
    __shared__ int lstart[BNODES];
    __shared__ int lcur[BNODES];
    const int t = threadIdx.x;
    const int b = blockIdx.x;
    const int base0 = b * ECAP;
    const int ecnt  = bfill[b];

    if (t < BNODES) cntS[t] = 0;
    __syncthreads();
    for (int i = t; i < ecnt; i += 1024)
        atomicAdd(&cntS[staging[base0 + i] >> 17], 1);
    __syncthreads();
    if (t < BNODES) scanS[t] = cntS[t];
    __syncthreads();
    for (int off = 1; off < BNODES; off <<= 1) {
        int xv = 0;
        if (t >= off && t < BNODES) xv = scanS[t - off];
        __syncthreads();
        if (t >= off && t < BNODES) scanS[t] += xv;
        __syncthreads();
    }
    if (t < BNODES) {
        const int st = scanS[t] - cntS[t];
        lstart[t] = st;
        lcur[t]   = st;
    }
    __syncthreads();
    for (int i = t; i < ecnt; i += 1024) {
        const unsigned ev = staging[base0 + i];
        const int lp = atomicAdd(&lcur[(int)(ev >> 17)], 1);
        ldst[lp] = (int)(ev & 0x1FFFFu);
    }
    __syncthreads();
    for (int i = t; i < ecnt; i += 1024)
        sdst[base0 + i] = ldst[i];       // contiguous coalesced segment write

    const int nbase = b * BNODES;
    if (t < BNODES && nbase + t < NN) {
        offs[nbase + t]   = base0 + lstart[t];
        counts[nbase + t] = cntS[t];
    }
}

// ------- dispatch 4: fused gather(mean)+MLP+heads ----------------------------------
// R14: aggregation rewritten as 8-rows-per-dwordx4. Lane l -> row-slot r=l>>3,
// feature-group g=l&7 (features g*8..g*8+7, 16B). One global_load_dwordx4 per wave
// fetches 8 neighbor rows (1 KB) vs the old 1 row per load + shfl broadcast.
// Index loads pipelined 2 iterations ahead; partials transposed back via LDS.
__global__ __launch_bounds__(256) void gather_head_kernel(
    const __half* __restrict__ h16,
    const int* __restrict__ counts, const int* __restrict__ offs,
    const int* __restrict__ sdst,
    const float* __restrict__ Wf1, const float* __restrict__ bf1,
    const float* __restrict__ Wf2, const float* __restrict__ bf2,
    const float* __restrict__ Ws1, const float* __restrict__ bs1,
    const float* __restrict__ Ws2, const float* __restrict__ bs2,
    const float* __restrict__ Wt1, const float* __restrict__ bt1,
    const float* __restrict__ Wt2, const float* __restrict__ bt2,
    float* __restrict__ out_scores, float* __restrict__ out_types)
{
    __shared__ float sa[4][H];
    __shared__ float sb[4][H];
    __shared__ float sp[4][8][H];        // 8 KB: per-wave row-slot partials
    const int tid  = threadIdx.x;
    const int slot = tid >> 6;
    const int f    = tid & 63;
    const int node = blockIdx.x * 4 + slot;   // grid 25000 -> node < NN always

    const int deg   = counts[node];
    const int start = offs[node];

    const int g = f & 7;                 // feature-group (bytes g*16 .. g*16+15 of row)
    const int r = f >> 3;                // row-slot within 8-row chunk

    const float selfv = __half2float(h16[((size_t)node << 6) + f]);  // issued early

    float acc[8];
    #pragma unroll
    for (int j = 0; j < 8; ++j) acc[j] = 0.0f;

    const __half* hbase = h16 + (g << 3);     // lane's 16B segment base within a row

    // depth-2 index pipeline: hv(i) address ready 2 iterations before use
    int d0 = (r < deg)     ? sdst[start + r]     : -1;
    int d1 = (8 + r < deg) ? sdst[start + 8 + r] : -1;

    #pragma unroll 2
    for (int base = 0; base < deg; base += 8) {
        int4 hv = make_int4(0, 0, 0, 0);
        if (d0 >= 0)
            hv = *reinterpret_cast<const int4*>(hbase + ((size_t)d0 << 6));
        const int nrow = base + 16 + r;
        const int nd = (nrow < deg) ? sdst[start + nrow] : -1;
        const __half2* ph = reinterpret_cast<const __half2*>(&hv);
        #pragma unroll
        for (int j = 0; j < 4; ++j) {
            const float2 f2 = __half22float2(ph[j]);
            acc[2 * j]     += f2.x;
            acc[2 * j + 1] += f2.y;
        }
        d0 = d1;
        d1 = nd;
    }

    // transpose partials back to lane=feature layout (cross-lane -> barrier)
    {
        float4* w0 = reinterpret_cast<float4*>(&sp[slot][r][g << 3]);
        w0[0] = make_float4(acc[0], acc[1], acc[2], acc[3]);
        w0[1] = make_float4(acc[4], acc[5], acc[6], acc[7]);
    }
    __syncthreads();
    float ssum = 0.0f;
    #pragma unroll
    for (int r2 = 0; r2 < 8; ++r2)
        ssum += sp[slot][r2][f];

    const float inv = 1.0f / fmaxf((float)deg, 1.0f);
    sa[slot][f] = selfv + ssum * inv;
    __syncthreads();

    {
        float a2 = bf1[f];
        #pragma unroll 8
        for (int k = 0; k < H; ++k)
            a2 = fmaf(sa[slot][k], Wf1[k * H + f], a2);
        sb[slot][f] = fmaxf(a2, 0.0f);
    }
    __syncthreads();

    {
        float a2 = bf2[f];
        #pragma unroll 8
        for (int k = 0; k < H; ++k)
            a2 = fmaf(sb[slot][k], Wf2[k * H + f], a2);
        sa[slot][f] = fmaxf(a2, 0.0f);
    }
    __syncthreads();

    {
        if (f < 32) {
            float a2 = bs1[f];
            #pragma unroll 8
            for (int k = 0; k < H; ++k)
                a2 = fmaf(sa[slot][k], Ws1[k * 32 + f], a2);
            sb[slot][f] = fmaxf(a2, 0.0f);
        } else {
            const int jj = f - 32;
            float a2 = bt1[jj];
            #pragma unroll 8
            for (int k = 0; k < H; ++k)
                a2 = fmaf(sa[slot][k], Wt1[k * 32 + jj], a2);
            sb[slot][32 + jj] = fmaxf(a2, 0.0f);
        }
    }
    __syncthreads();

    {
        if (f == 0) {
            float a2 = bs2[0];
            #pragma unroll 8
            for (int jj = 0; jj < 32; ++jj)
                a2 = fmaf(sb[slot][jj], Ws2[jj], a2);
            out_scores[node] = a2;
        } else if (f >= 1 && f < 5) {
            const int c = f - 1;
            float a2 = bt2[c];
            #pragma unroll 8
            for (int jj = 0; jj < 32; ++jj)
                a2 = fmaf(sb[slot][32 + jj], Wt2[jj * 4 + c], a2);
            out_types[node * 4 + c] = a2;
        }
    }
}

extern "C" void kernel_launch(void* const* d_in, const int* in_sizes, int n_in,
                              void* d_out, int out_size, void* d_ws, size_t ws_size,
                              hipStream_t stream)
{
    const float* x   = (const float*)d_in[0];
    const int*   adj = (const int*)  d_in[1];   // [2, E]: src = adj[0:E], dst = adj[E:2E]
    const float* W1  = (const float*)d_in[2];
    const float* b1  = (const float*)d_in[3];
    const float* W2  = (const float*)d_in[4];
    const float* b2  = (const float*)d_in[5];
    const float* Wf1 = (const float*)d_in[6];
    const float* bf1 = (const float*)d_in[7];
    const float* Wf2 = (const float*)d_in[8];
    const float* bf2 = (const float*)d_in[9];
    const float* Ws1 = (const float*)d_in[10];
    const float* bs1 = (const float*)d_in[11];
    const float* Ws2 = (const float*)d_in[12];
    const float* bs2 = (const float*)d_in[13];
    const float* Wt1 = (const float*)d_in[14];
    const float* bt1 = (const float*)d_in[15];
    const float* Wt2 = (const float*)d_in[16];
    const float* bt2 = (const float*)d_in[17];

    float* out_scores = (float*)d_out;          // [N]
    float* out_types  = out_scores + NN;        // [N,4]

    // ws: staging [NB*ECAP u32] | sdst [NB*ECAP] | h16 [NN*H half] | counts [NN]
    //     | offs [NN] | bfill [NB]
    unsigned* staging = (unsigned*)d_ws;
    int*      sdst    = (int*)(staging + (size_t)NB * ECAP);
    __half*   h16     = (__half*)(sdst + (size_t)NB * ECAP);
    int*      counts  = (int*)(h16 + (size_t)NN * H);
    int*      offs    = counts + NN;
    int*      bfill   = offs + NN;

    const int* src = adj;
    const int* dst = adj + NE;

    encoder_kernel<<<NN / 4, 256, 0, stream>>>(x, W1, b1, W2, b2, bfill, h16);
    partition_kernel<<<NPBLK, PTHREADS, 0, stream>>>(src, dst, bfill, staging);
    bucket_sort_kernel<<<NB, 1024, 0, stream>>>(staging, bfill, sdst, offs, counts);
    gather_head_kernel<<<NN / 4, 256, 0, stream>>>(h16, counts, offs, sdst,
                                                   Wf1, bf1, Wf2, bf2,
                                                   Ws1, bs1, Ws2, bs2,
                                                   Wt1, bt1, Wt2, bt2,
                                                   out_scores, out_types);
}

// Round 2
// 304.906 us; speedup vs baseline: 1.4323x; 1.3686x over previous
//
#include <hip/hip_runtime.h>
#include <hip/hip_fp16.h>

#define NN 100000
#define NE 3200000
#define H  64

#define BSHIFT 7
#define BNODES 128
#define NB ((NN + BNODES - 1) / BNODES)          // 782 buckets

#define PTHREADS 1024
#define PCHUNK   8192
#define PEPT     (PCHUNK / PTHREADS)             // 8
#define NPBLK    ((NE + PCHUNK - 1) / PCHUNK)    // 391

#define ECAP 5120                                // per-bucket slot (mean 4092, sd 64 -> +16 sigma)

#define GNB 16                                   // nodes per gather block (4 per wave)

// ------- dispatch 1: encoder (verified) + block 0: zero bfill AND prepack weights ---
// Prepacked layouts (in ws):
//   wf1t/wf2t/wht [16][64][4]: WT4[k4][f][j] = W[(4*k4+j)*H + f]   (wht = Ws1|Wt1 merged)
//   bhead[64] = bs1|bt1 ; wfin[5][32] (c=0: Ws2, c=1..4: Wt2 col c-1) ; bfin[5]
__global__ __launch_bounds__(256) void encoder_kernel(
    const float* __restrict__ x,
    const float* __restrict__ W1, const float* __restrict__ b1,
    const float* __restrict__ W2, const float* __restrict__ b2,
    const float* __restrict__ Wf1, const float* __restrict__ Wf2,
    const float* __restrict__ Ws1, const float* __restrict__ bs1,
    const float* __restrict__ Ws2, const float* __restrict__ bs2,
    const float* __restrict__ Wt1, const float* __restrict__ bt1,
    const float* __restrict__ Wt2, const float* __restrict__ bt2,
    int* __restrict__ bfill,
    float* __restrict__ wf1t, float* __restrict__ wf2t,
    float* __restrict__ wht,  float* __restrict__ bhead,
    float* __restrict__ wfin, float* __restrict__ bfin,
    __half* __restrict__ h16)
{
    __shared__ float sh1[4][H];
    const int tid  = threadIdx.x;
    const int slot = tid >> 6;
    const int f    = tid & 63;
    const int node = blockIdx.x * 4 + slot;      // grid 25000 -> node < NN always

    if (blockIdx.x == 0) {                       // ws is poisoned every launch
        for (int i = tid; i < NB; i += 256) bfill[i] = 0;
        for (int idx = tid; idx < 4096; idx += 256) {
            const int k4 = idx >> 8;
            const int ff = (idx >> 2) & 63;
            const int j  = idx & 3;
            wf1t[idx] = Wf1[k4 * 256 + j * 64 + ff];
            wf2t[idx] = Wf2[k4 * 256 + j * 64 + ff];
            wht[idx]  = (ff < 32) ? Ws1[k4 * 128 + j * 32 + ff]
                                  : Wt1[k4 * 128 + j * 32 + (ff - 32)];
        }
        if (tid < 64) bhead[tid] = (tid < 32) ? bs1[tid] : bt1[tid - 32];
        if (tid < 160) {
            const int c = tid >> 5, jj = tid & 31;
            wfin[tid] = (c == 0) ? Ws2[jj] : Wt2[jj * 4 + (c - 1)];
        }
        if (tid < 5) bfin[tid] = (tid == 0) ? bs2[0] : bt2[tid - 1];
    }

    {
        float acc = b1[f];
        #pragma unroll
        for (int k = 0; k < 6; ++k)
            acc = fmaf(x[node * 6 + k], W1[k * H + f], acc);
        sh1[slot][f] = fmaxf(acc, 0.0f);
    }
    __syncthreads();
    {
        float acc = b2[f];
        #pragma unroll 8
        for (int k = 0; k < H; ++k)
            acc = fmaf(sh1[slot][k], W2[k * H + f], acc);
        h16[node * H + f] = __float2half(acc);
    }
}

// ------- dispatch 2: partition -> fixed-slot bucket staging (verified R9 structure) --
__global__ __launch_bounds__(PTHREADS) void partition_kernel(
    const int* __restrict__ src, const int* __restrict__ dst,
    int* __restrict__ bfill, unsigned* __restrict__ staging)
{
    __shared__ unsigned stage[PCHUNK];   // 32 KB
    __shared__ int gpos[PCHUNK];         // 32 KB
    __shared__ int lh[NB];
    __shared__ int lcur[NB];
    __shared__ int gbase[NB];
    __shared__ int wtot[16];
    const int t = threadIdx.x;
    const int lane = t & 63;
    const int wid  = t >> 6;
    const int cbase = blockIdx.x * PCHUNK;
    const int cnt = min(PCHUNK, NE - cbase);

    for (int i = t; i < NB; i += PTHREADS) lh[i] = 0;
    __syncthreads();

    unsigned ent[PEPT];
    int bkt[PEPT];
    #pragma unroll
    for (int j = 0; j < PEPT; ++j) {
        const int idx = t + j * PTHREADS;
        if (idx < cnt) {
            const int s_ = src[cbase + idx];
            const int d_ = dst[cbase + idx];
            bkt[j] = s_ >> BSHIFT;
            ent[j] = (unsigned)d_ | ((unsigned)(s_ & (BNODES - 1)) << 17);
            atomicAdd(&lh[bkt[j]], 1);
        } else bkt[j] = -1;
    }
    __syncthreads();

    // wave-shfl exclusive scan over lh (verified R9)
    const int hv = (t < NB) ? lh[t] : 0;
    int incl = hv;
    #pragma unroll
    for (int off = 1; off < 64; off <<= 1) {
        const int n = __shfl_up(incl, off);
        if (lane >= off) incl += n;
    }
    if (lane == 63) wtot[wid] = incl;
    __syncthreads();
    if (wid == 0 && lane < 16) {
        const int v = wtot[lane];
        int s2 = v;
        #pragma unroll
        for (int off = 1; off < 16; off <<= 1) {
            const int n = __shfl_up(s2, off);
            if (lane >= off) s2 += n;
        }
        wtot[lane] = s2 - v;    // exclusive wave offsets
    }
    __syncthreads();
    if (t < NB) {
        const int excl = incl - hv + wtot[wid];
        lh[t]   = excl;
        lcur[t] = excl;
        gbase[t] = t * ECAP + ((hv > 0) ? atomicAdd(&bfill[t], hv) : 0);
    }
    __syncthreads();

    #pragma unroll
    for (int j = 0; j < PEPT; ++j) {
        if (bkt[j] >= 0) {
            const int lp = atomicAdd(&lcur[bkt[j]], 1);
            stage[lp] = ent[j];
            gpos[lp]  = gbase[bkt[j]] + (lp - lh[bkt[j]]);
        }
    }
    __syncthreads();

    for (int i = t; i < cnt; i += PTHREADS)
        staging[gpos[i]] = stage[i];
}

// ------- dispatch 3: bucket sort + per-node offs/counts (verified R13 structure) ----
__global__ __launch_bounds__(1024) void bucket_sort_kernel(
    const unsigned* __restrict__ staging, const int* __restrict__ bfill,
    int* __restrict__ sdst, int* __restrict__ offs, int* __restrict__ counts)
{
    __shared__ int ldst[ECAP];           // 20 KB
    __shared__ int cntS[BNODES];
    __shared__ int scanS[BNODES];
    __shared__ int lstart[BNODES];
    __shared__ int lcur[BNODES];
    const int t = threadIdx.x;
    const int b = blockIdx.x;
    const int base0 = b * ECAP;
    const int ecnt  = bfill[b];

    if (t < BNODES) cntS[t] = 0;
    __syncthreads();
    for (int i = t; i < ecnt; i += 1024)
        atomicAdd(&cntS[staging[base0 + i] >> 17], 1);
    __syncthreads();
    if (t < BNODES) scanS[t] = cntS[t];
    __syncthreads();
    for (int off = 1; off < BNODES; off <<= 1) {
        int xv = 0;
        if (t >= off && t < BNODES) xv = scanS[t - off];
        __syncthreads();
        if (t >= off && t < BNODES) scanS[t] += xv;
        __syncthreads();
    }
    if (t < BNODES) {
        const int st = scanS[t] - cntS[t];
        lstart[t] = st;
        lcur[t]   = st;
    }
    __syncthreads();
    for (int i = t; i < ecnt; i += 1024) {
        const unsigned ev = staging[base0 + i];
        const int lp = atomicAdd(&lcur[(int)(ev >> 17)], 1);
        ldst[lp] = (int)(ev & 0x1FFFFu);
    }
    __syncthreads();
    for (int i = t; i < ecnt; i += 1024)
        sdst[base0 + i] = ldst[i];       // contiguous coalesced segment write

    const int nbase = b * BNODES;
    if (t < BNODES && nbase + t < NN) {
        offs[nbase + t]   = base0 + lstart[t];
        counts[nbase + t] = cntS[t];
    }
}

// ------- dispatch 4: fused gather(mean)+MLP+heads ----------------------------------
// R15: VMEM-issue-bound fix. 16 nodes/block, 4 per wave. No __syncthreads at all:
// every LDS row is written and read by the same wave (same-wave DS ops are in order),
// so waves free-run (per-wave work ~ Poisson(128), balanced). Weights come from the
// prepacked WT4 layout: one dwordx4 = 4 k's of weights, reused across 4 nodes ->
// 16 weight VMEM per 64-k layer per wave (was 64 b32 per layer PER NODE, plus a
// divergent Ws1/Wt1 double-pass). VMEM/node: ~206 -> ~35.
__global__ __launch_bounds__(256) void gather_head_kernel(
    const __half* __restrict__ h16,
    const int* __restrict__ counts, const int* __restrict__ offs,
    const int* __restrict__ sdst,
    const float* __restrict__ wf1t, const float* __restrict__ bf1,
    const float* __restrict__ wf2t, const float* __restrict__ bf2,
    const float* __restrict__ wht,  const float* __restrict__ bhead,
    const float* __restrict__ wfin, const float* __restrict__ bfin,
    float* __restrict__ out_scores, float* __restrict__ out_types)
{
    __shared__ float sa[GNB][H];
    __shared__ float sb[GNB][H];
    __shared__ float sp[4][8][H];        // 8 KB: per-wave row-slot partials
    const int tid = threadIdx.x;
    const int wid = tid >> 6;
    const int f   = tid & 63;
    const int ln0 = wid * 4;                       // this wave's local row base
    const int n0  = blockIdx.x * GNB + ln0;        // first node of this wave

    const int g = f & 7;                 // feature-group (16B at g*16 within a row)
    const int r = f >> 3;                // row-slot within 8-row chunk
    const __half* hbase = h16 + (g << 3);

    #pragma unroll 1
    for (int j = 0; j < 4; ++j) {
        const int node  = n0 + j;
        const int deg   = counts[node];
        const int start = offs[node];
        const float selfv = __half2float(h16[((size_t)node << 6) + f]);

        float acc[8];
        #pragma unroll
        for (int u = 0; u < 8; ++u) acc[u] = 0.0f;

        // depth-2 index pipeline (verified R14)
        int d0 = (r < deg)     ? sdst[start + r]     : -1;
        int d1 = (8 + r < deg) ? sdst[start + 8 + r] : -1;

        #pragma unroll 2
        for (int base = 0; base < deg; base += 8) {
            int4 hv = make_int4(0, 0, 0, 0);
            if (d0 >= 0)
                hv = *reinterpret_cast<const int4*>(hbase + ((size_t)d0 << 6));
            const int nrow = base + 16 + r;
            const int nd = (nrow < deg) ? sdst[start + nrow] : -1;
            const __half2* ph = reinterpret_cast<const __half2*>(&hv);
            #pragma unroll
            for (int u = 0; u < 4; ++u) {
                const float2 f2 = __half22float2(ph[u]);
                acc[2 * u]     += f2.x;
                acc[2 * u + 1] += f2.y;
            }
            d0 = d1;
            d1 = nd;
        }

        // per-wave LDS transpose (verified R14 pattern; same-wave -> no barrier)
        {
            float4* w0 = reinterpret_cast<float4*>(&sp[wid][r][g << 3]);
            w0[0] = make_float4(acc[0], acc[1], acc[2], acc[3]);
            w0[1] = make_float4(acc[4], acc[5], acc[6], acc[7]);
        }
        float ssum = 0.0f;
        #pragma unroll
        for (int r2 = 0; r2 < 8; ++r2)
            ssum += sp[wid][r2][f];

        const float inv = 1.0f / fmaxf((float)deg, 1.0f);
        sa[ln0 + j][f] = selfv + ssum * inv;
    }

    // ---- layer 1: sa -> sb (relu), one weight dwordx4 feeds 4 k x 4 nodes ----
    {
        const float bb = bf1[f];
        float o0 = bb, o1 = bb, o2 = bb, o3 = bb;
        #pragma unroll
        for (int k4 = 0; k4 < 16; ++k4) {
            const float4 w  = *reinterpret_cast<const float4*>(&wf1t[(k4 * 64 + f) * 4]);
            const float4 a0 = *reinterpret_cast<const float4*>(&sa[ln0 + 0][k4 * 4]);
            const float4 a1 = *reinterpret_cast<const float4*>(&sa[ln0 + 1][k4 * 4]);
            const float4 a2 = *reinterpret_cast<const float4*>(&sa[ln0 + 2][k4 * 4]);
            const float4 a3 = *reinterpret_cast<const float4*>(&sa[ln0 + 3][k4 * 4]);
            o0 = fmaf(a0.x, w.x, o0); o0 = fmaf(a0.y, w.y, o0); o0 = fmaf(a0.z, w.z, o0); o0 = fmaf(a0.w, w.w, o0);
            o1 = fmaf(a1.x, w.x, o1); o1 = fmaf(a1.y, w.y, o1); o1 = fmaf(a1.z, w.z, o1); o1 = fmaf(a1.w, w.w, o1);
            o2 = fmaf(a2.x, w.x, o2); o2 = fmaf(a2.y, w.y, o2); o2 = fmaf(a2.z, w.z, o2); o2 = fmaf(a2.w, w.w, o2);
            o3 = fmaf(a3.x, w.x, o3); o3 = fmaf(a3.y, w.y, o3); o3 = fmaf(a3.z, w.z, o3); o3 = fmaf(a3.w, w.w, o3);
        }
        sb[ln0 + 0][f] = fmaxf(o0, 0.0f);
        sb[ln0 + 1][f] = fmaxf(o1, 0.0f);
        sb[ln0 + 2][f] = fmaxf(o2, 0.0f);
        sb[ln0 + 3][f] = fmaxf(o3, 0.0f);
    }

    // ---- layer 2: sb -> sa (relu) ----
    {
        const float bb = bf2[f];
        float o0 = bb, o1 = bb, o2 = bb, o3 = bb;
        #pragma unroll
        for (int k4 = 0; k4 < 16; ++k4) {
            const float4 w  = *reinterpret_cast<const float4*>(&wf2t[(k4 * 64 + f) * 4]);
            const float4 a0 = *reinterpret_cast<const float4*>(&sb[ln0 + 0][k4 * 4]);
            const float4 a1 = *reinterpret_cast<const float4*>(&sb[ln0 + 1][k4 * 4]);
            const float4 a2 = *reinterpret_cast<const float4*>(&sb[ln0 + 2][k4 * 4]);
            const float4 a3 = *reinterpret_cast<const float4*>(&sb[ln0 + 3][k4 * 4]);
            o0 = fmaf(a0.x, w.x, o0); o0 = fmaf(a0.y, w.y, o0); o0 = fmaf(a0.z, w.z, o0); o0 = fmaf(a0.w, w.w, o0);
            o1 = fmaf(a1.x, w.x, o1); o1 = fmaf(a1.y, w.y, o1); o1 = fmaf(a1.z, w.z, o1); o1 = fmaf(a1.w, w.w, o1);
            o2 = fmaf(a2.x, w.x, o2); o2 = fmaf(a2.y, w.y, o2); o2 = fmaf(a2.z, w.z, o2); o2 = fmaf(a2.w, w.w, o2);
            o3 = fmaf(a3.x, w.x, o3); o3 = fmaf(a3.y, w.y, o3); o3 = fmaf(a3.z, w.z, o3); o3 = fmaf(a3.w, w.w, o3);
        }
        sa[ln0 + 0][f] = fmaxf(o0, 0.0f);
        sa[ln0 + 1][f] = fmaxf(o1, 0.0f);
        sa[ln0 + 2][f] = fmaxf(o2, 0.0f);
        sa[ln0 + 3][f] = fmaxf(o3, 0.0f);
    }

    // ---- heads layer (merged Ws1|Wt1): sa -> sb (relu) ----
    {
        const float bb = bhead[f];
        float o0 = bb, o1 = bb, o2 = bb, o3 = bb;
        #pragma unroll
        for (int k4 = 0; k4 < 16; ++k4) {
            const float4 w  = *reinterpret_cast<const float4*>(&wht[(k4 * 64 + f) * 4]);
            const float4 a0 = *reinterpret_cast<const float4*>(&sa[ln0 + 0][k4 * 4]);
            const float4 a1 = *reinterpret_cast<const float4*>(&sa[ln0 + 1][k4 * 4]);
            const float4 a2 = *reinterpret_cast<const float4*>(&sa[ln0 + 2][k4 * 4]);
            const float4 a3 = *reinterpret_cast<const float4*>(&sa[ln0 + 3][k4 * 4]);
            o0 = fmaf(a0.x, w.x, o0); o0 = fmaf(a0.y, w.y, o0); o0 = fmaf(a0.z, w.z, o0); o0 = fmaf(a0.w, w.w, o0);
            o1 = fmaf(a1.x, w.x, o1); o1 = fmaf(a1.y, w.y, o1); o1 = fmaf(a1.z, w.z, o1); o1 = fmaf(a1.w, w.w, o1);
            o2 = fmaf(a2.x, w.x, o2); o2 = fmaf(a2.y, w.y, o2); o2 = fmaf(a2.z, w.z, o2); o2 = fmaf(a2.w, w.w, o2);
            o3 = fmaf(a3.x, w.x, o3); o3 = fmaf(a3.y, w.y, o3); o3 = fmaf(a3.z, w.z, o3); o3 = fmaf(a3.w, w.w, o3);
        }
        sb[ln0 + 0][f] = fmaxf(o0, 0.0f);
        sb[ln0 + 1][f] = fmaxf(o1, 0.0f);
        sb[ln0 + 2][f] = fmaxf(o2, 0.0f);
        sb[ln0 + 3][f] = fmaxf(o3, 0.0f);
    }

    // ---- final: lane (j = f>>4, c = f&15, active c<5); rotated start de-conflicts banks
    {
        const int j = f >> 4;
        const int c = f & 15;
        if (c < 5) {
            float a2 = bfin[c];
            const int off = (c == 0) ? 0 : 32;
            const int rot = ((c << 2) + (j << 3)) & 31;
            #pragma unroll 8
            for (int jj = 0; jj < 32; ++jj) {
                const int q = (jj + rot) & 31;
                a2 = fmaf(sb[ln0 + j][off + q], wfin[c * 32 + q], a2);
            }
            const int node = n0 + j;
            if (c == 0) out_scores[node] = a2;
            else        out_types[node * 4 + (c - 1)] = a2;
        }
    }
}

extern "C" void kernel_launch(void* const* d_in, const int* in_sizes, int n_in,
                              void* d_out, int out_size, void* d_ws, size_t ws_size,
                              hipStream_t stream)
{
    const float* x   = (const float*)d_in[0];
    const int*   adj = (const int*)  d_in[1];   // [2, E]: src = adj[0:E], dst = adj[E:2E]
    const float* W1  = (const float*)d_in[2];
    const float* b1  = (const float*)d_in[3];
    const float* W2  = (const float*)d_in[4];
    const float* b2  = (const float*)d_in[5];
    const float* Wf1 = (const float*)d_in[6];
    const float* bf1 = (const float*)d_in[7];
    const float* Wf2 = (const float*)d_in[8];
    const float* bf2 = (const float*)d_in[9];
    const float* Ws1 = (const float*)d_in[10];
    const float* bs1 = (const float*)d_in[11];
    const float* Ws2 = (const float*)d_in[12];
    const float* bs2 = (const float*)d_in[13];
    const float* Wt1 = (const float*)d_in[14];
    const float* bt1 = (const float*)d_in[15];
    const float* Wt2 = (const float*)d_in[16];
    const float* bt2 = (const float*)d_in[17];

    float* out_scores = (float*)d_out;          // [N]
    float* out_types  = out_scores + NN;        // [N,4]

    // ws: staging [NB*ECAP u32] | sdst [NB*ECAP] | h16 [NN*H half] | counts [NN]
    //     | offs [NN] | bfill [NB->784] | wf1t[4096] wf2t[4096] wht[4096]
    //     | bhead[64] wfin[160] bfin[5]
    unsigned* staging = (unsigned*)d_ws;
    int*      sdst    = (int*)(staging + (size_t)NB * ECAP);
    __half*   h16     = (__half*)(sdst + (size_t)NB * ECAP);
    int*      counts  = (int*)(h16 + (size_t)NN * H);
    int*      offs    = counts + NN;
    int*      bfill   = offs + NN;
    float*    wf1t    = (float*)(bfill + 784);   // 16B-aligned (checked)
    float*    wf2t    = wf1t + 4096;
    float*    wht     = wf2t + 4096;
    float*    bhead   = wht + 4096;
    float*    wfin    = bhead + 64;
    float*    bfin    = wfin + 160;

    const int* src = adj;
    const int* dst = adj + NE;

    encoder_kernel<<<NN / 4, 256, 0, stream>>>(x, W1, b1, W2, b2,
                                               Wf1, Wf2, Ws1, bs1, Ws2, bs2,
                                               Wt1, bt1, Wt2, bt2,
                                               bfill, wf1t, wf2t, wht, bhead, wfin, bfin,
                                               h16);
    partition_kernel<<<NPBLK, PTHREADS, 0, stream>>>(src, dst, bfill, staging);
    bucket_sort_kernel<<<NB, 1024, 0, stream>>>(staging, bfill, sdst, offs, counts);
    gather_head_kernel<<<NN / GNB, 256, 0, stream>>>(h16, counts, offs, sdst,
                                                     wf1t, bf1, wf2t, bf2,
                                                     wht, bhead, wfin, bfin,
                                                     out_scores, out_types);
}

// Round 3
// 278.713 us; speedup vs baseline: 1.5669x; 1.0940x over previous
//
#include <hip/hip_runtime.h>
#include <hip/hip_fp16.h>

#define NN 100000
#define NE 3200000
#define H  64

#define BSHIFT 7
#define BNODES 128
#define NB ((NN + BNODES - 1) / BNODES)          // 782 buckets

#define PTHREADS 1024
#define PCHUNK   8192
#define PEPT     (PCHUNK / PTHREADS)             // 8
#define NPBLK    ((NE + PCHUNK - 1) / PCHUNK)    // 391

#define ECAP 5120                                // per-bucket slot (padded total <= ~4600)

// ------- dispatch 1: encoder (verified math) + distributed prepack ------------------
// Prepack spread over blocks 0..47 (one entry/thread) to kill the single-block tail;
// block 48 zeroes bfill and packs the small tables.
__global__ __launch_bounds__(256) void encoder_kernel(
    const float* __restrict__ x,
    const float* __restrict__ W1, const float* __restrict__ b1,
    const float* __restrict__ W2, const float* __restrict__ b2,
    const float* __restrict__ Wf1, const float* __restrict__ Wf2,
    const float* __restrict__ Ws1, const float* __restrict__ bs1,
    const float* __restrict__ Ws2, const float* __restrict__ bs2,
    const float* __restrict__ Wt1, const float* __restrict__ bt1,
    const float* __restrict__ Wt2, const float* __restrict__ bt2,
    int* __restrict__ bfill,
    float* __restrict__ wf1t, float* __restrict__ wf2t,
    float* __restrict__ wht,  float* __restrict__ bhead,
    float* __restrict__ wfin, float* __restrict__ bfin,
    __half* __restrict__ h16)
{
    __shared__ float sh1[4][H];
    const int tid  = threadIdx.x;
    const int slot = tid >> 6;
    const int f    = tid & 63;
    const int node = blockIdx.x * 4 + slot;      // grid 25000 -> node < NN always

    if (blockIdx.x < 48) {                       // 48*256 = 12288 = 3*4096 entries
        const int e   = blockIdx.x * 256 + tid;
        const int a   = e >> 12;
        const int idx = e & 4095;
        const int k4  = idx >> 8;
        const int ff  = (idx >> 2) & 63;
        const int j   = idx & 3;
        if (a == 0)      wf1t[idx] = Wf1[k4 * 256 + j * 64 + ff];
        else if (a == 1) wf2t[idx] = Wf2[k4 * 256 + j * 64 + ff];
        else             wht[idx]  = (ff < 32) ? Ws1[k4 * 128 + j * 32 + ff]
                                               : Wt1[k4 * 128 + j * 32 + (ff - 32)];
    } else if (blockIdx.x == 48) {               // ws is poisoned every launch
        for (int i = tid; i < NB; i += 256) bfill[i] = 0;
        if (tid < 64) bhead[tid] = (tid < 32) ? bs1[tid] : bt1[tid - 32];
        if (tid < 160) {
            const int c = tid >> 5, jj = tid & 31;
            wfin[tid] = (c == 0) ? Ws2[jj] : Wt2[jj * 4 + (c - 1)];
        }
        if (tid < 5) bfin[tid] = (tid == 0) ? bs2[0] : bt2[tid - 1];
    }

    {
        float acc = b1[f];
        #pragma unroll
        for (int k = 0; k < 6; ++k)
            acc = fmaf(x[node * 6 + k], W1[k * H + f], acc);
        sh1[slot][f] = fmaxf(acc, 0.0f);
    }
    __syncthreads();
    {
        float acc = b2[f];
        #pragma unroll 8
        for (int k = 0; k < H; ++k)
            acc = fmaf(sh1[slot][k], W2[k * H + f], acc);
        h16[node * H + f] = __float2half(acc);
    }
}

// ------- dispatch 2: partition -> fixed-slot bucket staging (verified R9 structure) --
__global__ __launch_bounds__(PTHREADS) void partition_kernel(
    const int* __restrict__ src, const int* __restrict__ dst,
    int* __restrict__ bfill, unsigned* __restrict__ staging)
{
    __shared__ unsigned stage[PCHUNK];   // 32 KB
    __shared__ int gpos[PCHUNK];         // 32 KB
    __shared__ int lh[NB];
    __shared__ int lcur[NB];
    __shared__ int gbase[NB];
    __shared__ int wtot[16];
    const int t = threadIdx.x;
    const int lane = t & 63;
    const int wid  = t >> 6;
    const int cbase = blockIdx.x * PCHUNK;
    const int cnt = min(PCHUNK, NE - cbase);

    for (int i = t; i < NB; i += PTHREADS) lh[i] = 0;
    __syncthreads();

    unsigned ent[PEPT];
    int bkt[PEPT];
    #pragma unroll
    for (int j = 0; j < PEPT; ++j) {
        const int idx = t + j * PTHREADS;
        if (idx < cnt) {
            const int s_ = src[cbase + idx];
            const int d_ = dst[cbase + idx];
            bkt[j] = s_ >> BSHIFT;
            ent[j] = (unsigned)d_ | ((unsigned)(s_ & (BNODES - 1)) << 17);
            atomicAdd(&lh[bkt[j]], 1);
        } else bkt[j] = -1;
    }
    __syncthreads();

    // wave-shfl exclusive scan over lh (verified R9)
    const int hv = (t < NB) ? lh[t] : 0;
    int incl = hv;
    #pragma unroll
    for (int off = 1; off < 64; off <<= 1) {
        const int n = __shfl_up(incl, off);
        if (lane >= off) incl += n;
    }
    if (lane == 63) wtot[wid] = incl;
    __syncthreads();
    if (wid == 0 && lane < 16) {
        const int v = wtot[lane];
        int s2 = v;
        #pragma unroll
        for (int off = 1; off < 16; off <<= 1) {
            const int n = __shfl_up(s2, off);
            if (lane >= off) s2 += n;
        }
        wtot[lane] = s2 - v;    // exclusive wave offsets
    }
    __syncthreads();
    if (t < NB) {
        const int excl = incl - hv + wtot[wid];
        lh[t]   = excl;
        lcur[t] = excl;
        gbase[t] = t * ECAP + ((hv > 0) ? atomicAdd(&bfill[t], hv) : 0);
    }
    __syncthreads();

    #pragma unroll
    for (int j = 0; j < PEPT; ++j) {
        if (bkt[j] >= 0) {
            const int lp = atomicAdd(&lcur[bkt[j]], 1);
            stage[lp] = ent[j];
            gpos[lp]  = gbase[bkt[j]] + (lp - lh[bkt[j]]);
        }
    }
    __syncthreads();

    for (int i = t; i < cnt; i += PTHREADS)
        staging[gpos[i]] = stage[i];
}

// ------- dispatch 3: bucket sort + per-node offs/counts ------------------------------
// R16: per-node segment starts padded to multiples of 4 ints (16 B) so the gather can
// use dwordx4 index loads. Gap entries are garbage and always masked at consume.
__global__ __launch_bounds__(1024) void bucket_sort_kernel(
    const unsigned* __restrict__ staging, const int* __restrict__ bfill,
    int* __restrict__ sdst, int* __restrict__ offs, int* __restrict__ counts)
{
    __shared__ int ldst[ECAP];           // 20 KB
    __shared__ int cntS[BNODES];
    __shared__ int scanS[BNODES];
    __shared__ int lstart[BNODES];
    __shared__ int lcur[BNODES];
    const int t = threadIdx.x;
    const int b = blockIdx.x;
    const int base0 = b * ECAP;
    const int ecnt  = bfill[b];

    if (t < BNODES) cntS[t] = 0;
    __syncthreads();
    for (int i = t; i < ecnt; i += 1024)
        atomicAdd(&cntS[staging[base0 + i] >> 17], 1);
    __syncthreads();
    if (t < BNODES) scanS[t] = (cntS[t] + 3) & ~3;   // padded counts
    __syncthreads();
    for (int off = 1; off < BNODES; off <<= 1) {
        int xv = 0;
        if (t >= off && t < BNODES) xv = scanS[t - off];
        __syncthreads();
        if (t >= off && t < BNODES) scanS[t] += xv;
        __syncthreads();
    }
    if (t < BNODES) {
        const int st = scanS[t] - ((cntS[t] + 3) & ~3);
        lstart[t] = st;
        lcur[t]   = st;
    }
    __syncthreads();
    const int tot4 = scanS[BNODES - 1];              // padded total (<= ~4600 < ECAP)
    for (int i = t; i < ecnt; i += 1024) {
        const unsigned ev = staging[base0 + i];
        const int lp = atomicAdd(&lcur[(int)(ev >> 17)], 1);
        ldst[lp] = (int)(ev & 0x1FFFFu);
    }
    __syncthreads();
    for (int i = t; i < tot4; i += 1024)
        sdst[base0 + i] = ldst[i];       // contiguous write; gaps garbage (masked later)

    const int nbase = b * BNODES;
    if (t < BNODES && nbase + t < NN) {
        offs[nbase + t]   = base0 + lstart[t];
        counts[nbase + t] = cntS[t];
    }
}

// ------- dispatch 4: fused gather(mean)+MLP+heads ------------------------------------
// R16: latency-hiding gather. 64-thread blocks (1 wave, 4 nodes). Flattened chunk walk
// (32 edges/chunk) over the wave's 4 nodes with a software pipeline:
//   stage 0: idx dwordx4 for chunk t+1 in flight
//   stage 1: 4 row dwordx4 for chunk t+1 issued (bank B) while
//   stage 2: bank A (chunk t) is consumed; flush at node boundaries.
// Two register banks, all statically indexed. Invalid tail elements: index clamped
// to row 0, contribution masked with fmaf(m, v, acc), m in {0,1}.
#define ACC4(cv, u)                                                            \
    {                                                                          \
        const float m = (rem > (u)) ? 1.0f : 0.0f;                             \
        const __half2* ph = reinterpret_cast<const __half2*>(&(cv));           \
        const float2 p0 = __half22float2(ph[0]);                               \
        const float2 p1 = __half22float2(ph[1]);                               \
        const float2 p2 = __half22float2(ph[2]);                               \
        const float2 p3 = __half22float2(ph[3]);                               \
        acc0 = fmaf(m, p0.x, acc0); acc1 = fmaf(m, p0.y, acc1);                \
        acc2 = fmaf(m, p1.x, acc2); acc3 = fmaf(m, p1.y, acc3);                \
        acc4 = fmaf(m, p2.x, acc4); acc5 = fmaf(m, p2.y, acc5);                \
        acc6 = fmaf(m, p3.x, acc6); acc7 = fmaf(m, p3.y, acc7);                \
    }

#define FLUSHN(jj)                                                             \
    {                                                                          \
        float4* w0 = reinterpret_cast<float4*>(&sp[r][g << 3]);                \
        w0[0] = make_float4(acc0, acc1, acc2, acc3);                           \
        w0[1] = make_float4(acc4, acc5, acc6, acc7);                           \
        const float ssum = sp[0][f] + sp[1][f] + sp[2][f] + sp[3][f]           \
                         + sp[4][f] + sp[5][f] + sp[6][f] + sp[7][f];          \
        const int dgj = DGf(jj);                                               \
        sa[jj][f] = SVf(jj) + ssum * (1.0f / fmaxf((float)dgj, 1.0f));         \
        acc0 = acc1 = acc2 = acc3 = acc4 = acc5 = acc6 = acc7 = 0.0f;          \
    }

#define GSTEP(c0, c1, c2, c3, n0_, n1_, n2_, n3_)                              \
    {                                                                          \
        if (jn < 4) { /* fill bank N for chunk (jn,bn) */                      \
            const int rem = DGf(jn) - bn - 4 * r;                              \
            const int i0 = (rem > 0) ? idxN.x : 0;                             \
            const int i1 = (rem > 1) ? idxN.y : 0;                             \
            const int i2 = (rem > 2) ? idxN.z : 0;                             \
            const int i3 = (rem > 3) ? idxN.w : 0;                             \
            n0_ = *reinterpret_cast<const int4*>(hbase + ((size_t)i0 << 6));   \
            n1_ = *reinterpret_cast<const int4*>(hbase + ((size_t)i1 << 6));   \
            n2_ = *reinterpret_cast<const int4*>(hbase + ((size_t)i2 << 6));   \
            n3_ = *reinterpret_cast<const int4*>(hbase + ((size_t)i3 << 6));   \
        }                                                                      \
        int jm = jn, bm = bn; adv(jm, bm);                                     \
        idxN = IDXL(jm, bm);                                                   \
        { /* consume bank C for chunk (jc,bc) */                               \
            const int rem = DGf(jc) - bc - 4 * r;                              \
            ACC4(c0, 0); ACC4(c1, 1); ACC4(c2, 2); ACC4(c3, 3);                \
        }                                                                      \
        if (jn != jc) FLUSHN(jc);                                              \
        jc = jn; bc = bn; jn = jm; bn = bm;                                    \
    }

__global__ __launch_bounds__(64, 4) void gather_head_kernel(
    const __half* __restrict__ h16,
    const int* __restrict__ counts, const int* __restrict__ offs,
    const int* __restrict__ sdst,
    const float* __restrict__ wf1t, const float* __restrict__ bf1,
    const float* __restrict__ wf2t, const float* __restrict__ bf2,
    const float* __restrict__ wht,  const float* __restrict__ bhead,
    const float* __restrict__ wfin, const float* __restrict__ bfin,
    float* __restrict__ out_scores, float* __restrict__ out_types)
{
    __shared__ float sa[4][H];
    __shared__ float sb[4][H];
    __shared__ float sp[8][H];           // 2 KB row-slot partials
    const int f  = threadIdx.x;          // 0..63
    const int n0 = blockIdx.x * 4;       // grid 25000 -> n0+3 < NN always
    const int g  = f & 7;                // feature-group (16B at g*16 within a row)
    const int r  = f >> 3;               // row-slot (4 consecutive edges per slot)
    const __half* __restrict__ hbase = h16 + (g << 3);

    const int dg0 = counts[n0 + 0], dg1 = counts[n0 + 1],
              dg2 = counts[n0 + 2], dg3 = counts[n0 + 3];
    const int st0 = offs[n0 + 0], st1 = offs[n0 + 1],
              st2 = offs[n0 + 2], st3 = offs[n0 + 3];

    const float sv0 = __half2float(h16[((size_t)(n0 + 0) << 6) + f]);
    const float sv1 = __half2float(h16[((size_t)(n0 + 1) << 6) + f]);
    const float sv2 = __half2float(h16[((size_t)(n0 + 2) << 6) + f]);
    const float sv3 = __half2float(h16[((size_t)(n0 + 3) << 6) + f]);
    sa[0][f] = sv0; sa[1][f] = sv1; sa[2][f] = sv2; sa[3][f] = sv3;  // deg-0 default

    auto DGf = [&](int j) { return j == 0 ? dg0 : j == 1 ? dg1 : j == 2 ? dg2 : dg3; };
    auto STf = [&](int j) { return j == 0 ? st0 : j == 1 ? st1 : j == 2 ? st2 : st3; };
    auto SVf = [&](int j) { return j == 0 ? sv0 : j == 1 ? sv1 : j == 2 ? sv2 : sv3; };
    auto adv = [&](int& j, int& b) {
        if (j >= 4) return;
        b += 32;
        if (b >= DGf(j)) { b = 0; do { ++j; } while (j < 4 && DGf(j) == 0); }
    };
    auto IDXL = [&](int j, int b) -> int4 {   // 16B-aligned: starts padded to 4 ints
        if (j < 4) return *reinterpret_cast<const int4*>(&sdst[STf(j) + b + 4 * r]);
        return make_int4(0, 0, 0, 0);
    };

    float acc0 = 0.f, acc1 = 0.f, acc2 = 0.f, acc3 = 0.f,
          acc4 = 0.f, acc5 = 0.f, acc6 = 0.f, acc7 = 0.f;
    int4 A0 = make_int4(0,0,0,0), A1 = A0, A2 = A0, A3 = A0;
    int4 B0 = A0, B1 = A0, B2 = A0, B3 = A0;

    // --- pipeline prologue ---
    int jc = 0, bc = 0;
    while (jc < 4 && DGf(jc) == 0) ++jc;
    int jn = jc, bn = bc; adv(jn, bn);
    int4 idxC = IDXL(jc, bc);
    int4 idxN = IDXL(jn, bn);
    if (jc < 4) {                         // fill bank A for first chunk
        const int rem = DGf(jc) - bc - 4 * r;
        const int i0 = (rem > 0) ? idxC.x : 0;
        const int i1 = (rem > 1) ? idxC.y : 0;
        const int i2 = (rem > 2) ? idxC.z : 0;
        const int i3 = (rem > 3) ? idxC.w : 0;
        A0 = *reinterpret_cast<const int4*>(hbase + ((size_t)i0 << 6));
        A1 = *reinterpret_cast<const int4*>(hbase + ((size_t)i1 << 6));
        A2 = *reinterpret_cast<const int4*>(hbase + ((size_t)i2 << 6));
        A3 = *reinterpret_cast<const int4*>(hbase + ((size_t)i3 << 6));
    }

    while (jc < 4) {
        GSTEP(A0, A1, A2, A3, B0, B1, B2, B3);
        if (jc >= 4) break;
        GSTEP(B0, B1, B2, B3, A0, A1, A2, A3);
    }

    // ---- layer 1: sa -> sb (relu), one weight dwordx4 feeds 4 k x 4 nodes ----
    {
        const float bb = bf1[f];
        float o0 = bb, o1 = bb, o2 = bb, o3 = bb;
        #pragma unroll
        for (int k4 = 0; k4 < 16; ++k4) {
            const float4 w  = *reinterpret_cast<const float4*>(&wf1t[(k4 * 64 + f) * 4]);
            const float4 a0 = *reinterpret_cast<const float4*>(&sa[0][k4 * 4]);
            const float4 a1 = *reinterpret_cast<const float4*>(&sa[1][k4 * 4]);
            const float4 a2 = *reinterpret_cast<const float4*>(&sa[2][k4 * 4]);
            const float4 a3 = *reinterpret_cast<const float4*>(&sa[3][k4 * 4]);
            o0 = fmaf(a0.x, w.x, o0); o0 = fmaf(a0.y, w.y, o0); o0 = fmaf(a0.z, w.z, o0); o0 = fmaf(a0.w, w.w, o0);
            o1 = fmaf(a1.x, w.x, o1); o1 = fmaf(a1.y, w.y, o1); o1 = fmaf(a1.z, w.z, o1); o1 = fmaf(a1.w, w.w, o1);
            o2 = fmaf(a2.x, w.x, o2); o2 = fmaf(a2.y, w.y, o2); o2 = fmaf(a2.z, w.z, o2); o2 = fmaf(a2.w, w.w, o2);
            o3 = fmaf(a3.x, w.x, o3); o3 = fmaf(a3.y, w.y, o3); o3 = fmaf(a3.z, w.z, o3); o3 = fmaf(a3.w, w.w, o3);
        }
        sb[0][f] = fmaxf(o0, 0.0f);
        sb[1][f] = fmaxf(o1, 0.0f);
        sb[2][f] = fmaxf(o2, 0.0f);
        sb[3][f] = fmaxf(o3, 0.0f);
    }

    // ---- layer 2: sb -> sa (relu) ----
    {
        const float bb = bf2[f];
        float o0 = bb, o1 = bb, o2 = bb, o3 = bb;
        #pragma unroll
        for (int k4 = 0; k4 < 16; ++k4) {
            const float4 w  = *reinterpret_cast<const float4*>(&wf2t[(k4 * 64 + f) * 4]);
            const float4 a0 = *reinterpret_cast<const float4*>(&sb[0][k4 * 4]);
            const float4 a1 = *reinterpret_cast<const float4*>(&sb[1][k4 * 4]);
            const float4 a2 = *reinterpret_cast<const float4*>(&sb[2][k4 * 4]);
            const float4 a3 = *reinterpret_cast<const float4*>(&sb[3][k4 * 4]);
            o0 = fmaf(a0.x, w.x, o0); o0 = fmaf(a0.y, w.y, o0); o0 = fmaf(a0.z, w.z, o0); o0 = fmaf(a0.w, w.w, o0);
            o1 = fmaf(a1.x, w.x, o1); o1 = fmaf(a1.y, w.y, o1); o1 = fmaf(a1.z, w.z, o1); o1 = fmaf(a1.w, w.w, o1);
            o2 = fmaf(a2.x, w.x, o2); o2 = fmaf(a2.y, w.y, o2); o2 = fmaf(a2.z, w.z, o2); o2 = fmaf(a2.w, w.w, o2);
            o3 = fmaf(a3.x, w.x, o3); o3 = fmaf(a3.y, w.y, o3); o3 = fmaf(a3.z, w.z, o3); o3 = fmaf(a3.w, w.w, o3);
        }
        sa[0][f] = fmaxf(o0, 0.0f);
        sa[1][f] = fmaxf(o1, 0.0f);
        sa[2][f] = fmaxf(o2, 0.0f);
        sa[3][f] = fmaxf(o3, 0.0f);
    }

    // ---- heads layer (merged Ws1|Wt1): sa -> sb (relu) ----
    {
        const float bb = bhead[f];
        float o0 = bb, o1 = bb, o2 = bb, o3 = bb;
        #pragma unroll
        for (int k4 = 0; k4 < 16; ++k4) {
            const float4 w  = *reinterpret_cast<const float4*>(&wht[(k4 * 64 + f) * 4]);
            const float4 a0 = *reinterpret_cast<const float4*>(&sa[0][k4 * 4]);
            const float4 a1 = *reinterpret_cast<const float4*>(&sa[1][k4 * 4]);
            const float4 a2 = *reinterpret_cast<const float4*>(&sa[2][k4 * 4]);
            const float4 a3 = *reinterpret_cast<const float4*>(&sa[3][k4 * 4]);
            o0 = fmaf(a0.x, w.x, o0); o0 = fmaf(a0.y, w.y, o0); o0 = fmaf(a0.z, w.z, o0); o0 = fmaf(a0.w, w.w, o0);
            o1 = fmaf(a1.x, w.x, o1); o1 = fmaf(a1.y, w.y, o1); o1 = fmaf(a1.z, w.z, o1); o1 = fmaf(a1.w, w.w, o1);
            o2 = fmaf(a2.x, w.x, o2); o2 = fmaf(a2.y, w.y, o2); o2 = fmaf(a2.z, w.z, o2); o2 = fmaf(a2.w, w.w, o2);
            o3 = fmaf(a3.x, w.x, o3); o3 = fmaf(a3.y, w.y, o3); o3 = fmaf(a3.z, w.z, o3); o3 = fmaf(a3.w, w.w, o3);
        }
        sb[0][f] = fmaxf(o0, 0.0f);
        sb[1][f] = fmaxf(o1, 0.0f);
        sb[2][f] = fmaxf(o2, 0.0f);
        sb[3][f] = fmaxf(o3, 0.0f);
    }

    // ---- final: j = f>>4 (node), c = f&15 (output, active c<5); rotated start ----
    {
        const int j = f >> 4;
        const int c = f & 15;
        if (c < 5) {
            float a2 = bfin[c];
            const int off = (c == 0) ? 0 : 32;
            const int rot = ((c << 2) + (j << 3)) & 31;
            #pragma unroll 8
            for (int jj = 0; jj < 32; ++jj) {
                const int q = (jj + rot) & 31;
                a2 = fmaf(sb[j][off + q], wfin[c * 32 + q], a2);
            }
            const int node = n0 + j;
            if (c == 0) out_scores[node] = a2;
            else        out_types[node * 4 + (c - 1)] = a2;
        }
    }
}

#undef GSTEP
#undef FLUSHN
#undef ACC4

extern "C" void kernel_launch(void* const* d_in, const int* in_sizes, int n_in,
                              void* d_out, int out_size, void* d_ws, size_t ws_size,
                              hipStream_t stream)
{
    const float* x   = (const float*)d_in[0];
    const int*   adj = (const int*)  d_in[1];   // [2, E]: src = adj[0:E], dst = adj[E:2E]
    const float* W1  = (const float*)d_in[2];
    const float* b1  = (const float*)d_in[3];
    const float* W2  = (const float*)d_in[4];
    const float* b2  = (const float*)d_in[5];
    const float* Wf1 = (const float*)d_in[6];
    const float* bf1 = (const float*)d_in[7];
    const float* Wf2 = (const float*)d_in[8];
    const float* bf2 = (const float*)d_in[9];
    const float* Ws1 = (const float*)d_in[10];
    const float* bs1 = (const float*)d_in[11];
    const float* Ws2 = (const float*)d_in[12];
    const float* bs2 = (const float*)d_in[13];
    const float* Wt1 = (const float*)d_in[14];
    const float* bt1 = (const float*)d_in[15];
    const float* Wt2 = (const float*)d_in[16];
    const float* bt2 = (const float*)d_in[17];

    float* out_scores = (float*)d_out;          // [N]
    float* out_types  = out_scores + NN;        // [N,4]

    // ws: staging [NB*ECAP u32] | sdst [NB*ECAP] | h16 [NN*H half] | counts [NN]
    //     | offs [NN] | bfill [784] | wf1t[4096] wf2t[4096] wht[4096]
    //     | bhead[64] wfin[160] bfin[5]
    unsigned* staging = (unsigned*)d_ws;
    int*      sdst    = (int*)(staging + (size_t)NB * ECAP);
    __half*   h16     = (__half*)(sdst + (size_t)NB * ECAP);
    int*      counts  = (int*)(h16 + (size_t)NN * H);
    int*      offs    = counts + NN;
    int*      bfill   = offs + NN;
    float*    wf1t    = (float*)(bfill + 784);   // 16B-aligned
    float*    wf2t    = wf1t + 4096;
    float*    wht     = wf2t + 4096;
    float*    bhead   = wht + 4096;
    float*    wfin    = bhead + 64;
    float*    bfin    = wfin + 160;

    const int* src = adj;
    const int* dst = adj + NE;

    encoder_kernel<<<NN / 4, 256, 0, stream>>>(x, W1, b1, W2, b2,
                                               Wf1, Wf2, Ws1, bs1, Ws2, bs2,
                                               Wt1, bt1, Wt2, bt2,
                                               bfill, wf1t, wf2t, wht, bhead, wfin, bfin,
                                               h16);
    partition_kernel<<<NPBLK, PTHREADS, 0, stream>>>(src, dst, bfill, staging);
    bucket_sort_kernel<<<NB, 1024, 0, stream>>>(staging, bfill, sdst, offs, counts);
    gather_head_kernel<<<NN / 4, 64, 0, stream>>>(h16, counts, offs, sdst,
                                                  wf1t, bf1, wf2t, bf2,
                                                  wht, bhead, wfin, bfin,
                                                  out_scores, out_types);
}